// Round 16
// baseline (5519.576 us; speedup 1.0000x reference)
//
#include <hip/hip_runtime.h>
#include <stdint.h>
#include <math.h>

#define HW 48
#define CIN 1280
#define HID 256
#define NA 9
#define NPOS (HW*HW)       // 2304
#define NANCH (NA*NPOS)    // 20736
#define KTOT 11520
#define WND 640

// ---------------- workspace layout (bytes) ----------------
#define OFF_W1T   ((size_t)0)                    // 11520*256*4 = 11796480
#define OFF_H64   (OFF_W1T + 11796480ull)        // 4*256*2304*8 = 18874368
#define OFF_H32   (OFF_H64 + 18874368ull)        // 256*2304*4 = 2359296 (batch1 only)
#define OFF_K64   (OFF_H32 + 2359296ull)         // 4*20736*8 = 663552
#define OFF_K32   (OFF_K64 + 663552ull)          // 20736*4 = 82944 (batch1 only)
#define OFF_S64   (OFF_K32 + 82944ull)           // 20480
#define OFF_S32   (OFF_S64 + 20480ull)           // 10240
#define OFF_WIDX  (OFF_S32 + 10240ull)           // 10240
#define OFF_SSC   (OFF_WIDX + 10240ull)          // 8192
#define OFF_SIDX  (OFF_SSC + 8192ull)            // 8192
#define OFF_SBX   (OFF_SIDX + 8192ull)           // 32768

__device__ __forceinline__ float npmul(float a, float b) { return __fmul_rn(a, b); }
__device__ __forceinline__ float npadd(float a, float b) { return __fadd_rn(a, b); }
__device__ __forceinline__ float npsub(float a, float b) { return __fsub_rn(a, b); }

// ---------------- W1 [256][11520] -> W1t [11520][256] (bit copy) ----------------
__global__ __launch_bounds__(256) void k_wt(const float* __restrict__ W1,
                                            float* __restrict__ W1t) {
  __shared__ float tile[32][73];
  const int co0 = blockIdx.x * 32;
  const int kt0 = blockIdx.y * 72;
  for (int u = threadIdx.x; u < 32*72; u += 256) {
    int co = u / 72, kt = u % 72;
    tile[co][kt] = W1[(size_t)(co0+co)*KTOT + kt0 + kt];
  }
  __syncthreads();
  for (int u = threadIdx.x; u < 32*72; u += 256) {
    int co = u % 32, kt = u / 32;
    W1t[(size_t)(kt0+kt)*256 + co0 + co] = tile[co][kt];
  }
}

// ---------------- unified conv: z<4 = f64 (batch z), z==4 = f32 (batch 1) --------
// LDS tiles staged as f64 (f32->f64 exact). f64 path uses doubles directly;
// f32 path converts back per use ((float)(double)x bit-exact). Chains identical
// to R15: f64 = per-tap c-chains summed in t order; f32 = single (t,c) chain.
__global__ __launch_bounds__(256) void k_conv(const float* __restrict__ W1t,
                                              const float* __restrict__ in,
                                              const float* __restrict__ b1,
                                              double* __restrict__ h64,
                                              float* __restrict__ h32) {
  __shared__ __align__(16) double As[16][68];
  __shared__ __align__(16) double Bs[16][68];
  const int z   = blockIdx.z;
  const int co0 = blockIdx.x * 64;
  const int p0  = blockIdx.y * 64;
  const int tid = threadIdx.x;
  const int col = (tid % 16) * 4;   // co in tile
  const int pl  = (tid / 16) * 4;   // p  in tile
  const int cA  = tid & 63;         // co for A-stage
  const int kA0 = tid >> 6;
  const int pp  = tid & 63;         // p for B-stage
  const int kB0 = tid >> 6;
  const int pB  = p0 + pp;
  const int yB  = pB / HW;
  const int xB  = pB - yB * HW;

  if (z < 4) {
    // ================= f64 path, batch b = z =================
    const int b = z;
    const size_t bbase = (size_t)b * CIN * NPOS;
    double run[4][4], tap[4][4];
    for (int t = 0; t < 9; ++t) {
      const int dy = t / 3 - 1;
      const int dx = t % 3 - 1;
      const int yy = yB + dy;
      const int xx = xB + dx;
      const bool vB = ((unsigned)yy < (unsigned)HW) && ((unsigned)xx < (unsigned)HW);
      const size_t inoff = bbase + (size_t)(vB ? (yy*HW + xx) : 0);
      #pragma unroll
      for (int i = 0; i < 4; ++i)
        #pragma unroll
        for (int j = 0; j < 4; ++j) tap[i][j] = 0.0;

      for (int c0 = 0; c0 < CIN; c0 += 16) {
        #pragma unroll
        for (int r = 0; r < 4; ++r)
          As[kA0 + 4*r][cA] =
            (double)W1t[((size_t)(c0 + kA0 + 4*r)*9 + t)*256 + co0 + cA];
        #pragma unroll
        for (int r = 0; r < 4; ++r) {
          const int kc = kB0 + 4*r;
          Bs[kc][pp] = vB ? (double)in[inoff + (size_t)(c0 + kc)*NPOS] : 0.0;
        }
        __syncthreads();
        #pragma unroll
        for (int kc = 0; kc < 16; ++kc) {
          const double2 a01 = *(const double2*)&As[kc][col];
          const double2 a23 = *(const double2*)&As[kc][col+2];
          const double2 b01 = *(const double2*)&Bs[kc][pl];
          const double2 b23 = *(const double2*)&Bs[kc][pl+2];
          const double av[4] = {a01.x, a01.y, a23.x, a23.y};
          const double bv[4] = {b01.x, b01.y, b23.x, b23.y};
          #pragma unroll
          for (int i = 0; i < 4; ++i)
            #pragma unroll
            for (int j = 0; j < 4; ++j)
              tap[i][j] = fma(av[i], bv[j], tap[i][j]);
        }
        __syncthreads();
      }
      if (t == 0) {
        #pragma unroll
        for (int i = 0; i < 4; ++i)
          #pragma unroll
          for (int j = 0; j < 4; ++j) run[i][j] = tap[i][j];
      } else {
        #pragma unroll
        for (int i = 0; i < 4; ++i)
          #pragma unroll
          for (int j = 0; j < 4; ++j) run[i][j] = run[i][j] + tap[i][j];
      }
    }
    #pragma unroll
    for (int i = 0; i < 4; ++i) {
      const int co = co0 + col + i;
      const double bias = (double)b1[co];
      #pragma unroll
      for (int j = 0; j < 4; ++j) {
        double v = run[i][j] + bias;
        v = (v >= 0.0) ? v : 0.01*v;
        h64[((size_t)b*HID + co)*NPOS + p0 + pl + j] = v;
      }
    }
  } else {
    // ================= f32 path, batch 1 only =================
    const size_t bbase = (size_t)1 * CIN * NPOS;
    float acc[4][4];
    #pragma unroll
    for (int i = 0; i < 4; ++i)
      #pragma unroll
      for (int j = 0; j < 4; ++j) acc[i][j] = 0.f;
    for (int t = 0; t < 9; ++t) {
      const int dy = t / 3 - 1;
      const int dx = t % 3 - 1;
      const int yy = yB + dy;
      const int xx = xB + dx;
      const bool vB = ((unsigned)yy < (unsigned)HW) && ((unsigned)xx < (unsigned)HW);
      const size_t inoff = bbase + (size_t)(vB ? (yy*HW + xx) : 0);
      for (int c0 = 0; c0 < CIN; c0 += 16) {
        #pragma unroll
        for (int r = 0; r < 4; ++r)
          As[kA0 + 4*r][cA] =
            (double)W1t[((size_t)(c0 + kA0 + 4*r)*9 + t)*256 + co0 + cA];
        #pragma unroll
        for (int r = 0; r < 4; ++r) {
          const int kc = kB0 + 4*r;
          Bs[kc][pp] = vB ? (double)in[inoff + (size_t)(c0 + kc)*NPOS] : 0.0;
        }
        __syncthreads();
        #pragma unroll
        for (int kc = 0; kc < 16; ++kc) {
          const double2 a01 = *(const double2*)&As[kc][col];
          const double2 a23 = *(const double2*)&As[kc][col+2];
          const double2 b01 = *(const double2*)&Bs[kc][pl];
          const double2 b23 = *(const double2*)&Bs[kc][pl+2];
          const float av[4] = {(float)a01.x, (float)a01.y, (float)a23.x, (float)a23.y};
          const float bv[4] = {(float)b01.x, (float)b01.y, (float)b23.x, (float)b23.y};
          #pragma unroll
          for (int i = 0; i < 4; ++i)
            #pragma unroll
            for (int j = 0; j < 4; ++j)
              acc[i][j] = fmaf(av[i], bv[j], acc[i][j]);
        }
        __syncthreads();
      }
    }
    #pragma unroll
    for (int i = 0; i < 4; ++i) {
      const int co = co0 + col + i;
      const float bias = b1[co];
      #pragma unroll
      for (int j = 0; j < 4; ++j) {
        float v = acc[i][j] + bias;
        v = (v >= 0.f) ? v : 0.01f*v;
        h32[(size_t)co*NPOS + p0 + pl + j] = v;
      }
    }
  }
}

// ---------------- head64: one thread per (p, a2) — identical chain ----------------
__global__ __launch_bounds__(256) void k_head64(const double* __restrict__ h64,
                                                const float* __restrict__ Wh,
                                                const float* __restrict__ bh,
                                                double* __restrict__ key64) {
  const int b = blockIdx.y;
  const int gid = blockIdx.x * 256 + threadIdx.x;   // 81*256 = 20736 exact
  const int a2 = gid / NPOS;
  const int p  = gid - a2 * NPOS;
  const double* hp = h64 + (size_t)b*HID*NPOS + p;
  const float*  wp = Wh + (size_t)(a2*5)*256;
  double acc = 0.0;
  for (int k = 0; k < 256; ++k)
    acc = fma(hp[(size_t)k*NPOS], (double)wp[k], acc);
  const double c = acc + (double)bh[a2*5];
  const double s = 1.0 / (1.0 + exp(-c));
  key64[(size_t)b*NANCH + gid] = (s > 0.5) ? s : -1.0;
}

// ---------------- head32 (batch1): one thread per (p, a2) ----------------
__global__ __launch_bounds__(256) void k_head32(const float* __restrict__ h32,
                                                const float* __restrict__ Wh,
                                                const float* __restrict__ bh,
                                                float* __restrict__ key32) {
  const int gid = blockIdx.x * 256 + threadIdx.x;   // 20736 exact
  const int a2 = gid / NPOS;
  const int p  = gid - a2 * NPOS;
  const float* hp = h32 + p;
  const float* wp = Wh + (size_t)(a2*5)*256;
  float acc = 0.f;
  for (int k = 0; k < 256; ++k)
    acc = fmaf(hp[(size_t)k*NPOS], wp[k], acc);
  const float c = npadd(acc, bh[a2*5]);
  const float t = (float)exp(-(double)c);
  const float s = __fdiv_rn(1.0f, npadd(1.0f, t));
  key32[gid] = (s > 0.5f) ? s : -1.0f;
}

// ---------------- rank-select top-640 by f64 key (desc, index-asc ties) -----------
__global__ __launch_bounds__(256) void k_rank(const double* __restrict__ key64,
                                              const float* __restrict__ key32,
                                              double* __restrict__ s64,
                                              float* __restrict__ s32,
                                              int* __restrict__ widx) {
  __shared__ double tile[1024];
  const int b = blockIdx.y;
  const int i = blockIdx.x * 256 + threadIdx.x;
  const double ki = key64[(size_t)b*NANCH + i];
  int rank = 0;
  for (int j0 = 0; j0 < NANCH; j0 += 1024) {
    const int lim = (NANCH - j0 < 1024) ? (NANCH - j0) : 1024;
    for (int u = threadIdx.x; u < 1024; u += 256) {
      const int j = j0 + u;
      tile[u] = (j < NANCH) ? key64[(size_t)b*NANCH + j] : -1.0e300;
    }
    __syncthreads();
    for (int u = 0; u < lim; ++u) {
      const double kj = tile[u];
      const int j = j0 + u;
      if (kj > ki || (kj == ki && j < i)) ++rank;
    }
    __syncthreads();
  }
  if (rank < WND) {
    s64[(size_t)b*WND + rank] = ki;
    widx[(size_t)b*WND + rank] = i;
    if (b == 1) s32[(size_t)b*WND + rank] = key32[i];
  }
}

// ---------------- hybrid fix (LDS-staged): batch-1 discordances -> f32 order ------
__global__ __launch_bounds__(256) void k_fix(const double* __restrict__ s64,
                                             const float* __restrict__ s32,
                                             const int* __restrict__ widx,
                                             float* __restrict__ ssc,
                                             int* __restrict__ sidx) {
  __shared__ double k6[WND];
  __shared__ float  k3[WND];
  __shared__ int    ix[WND];
  const int b = blockIdx.x;
  for (int u = threadIdx.x; u < WND; u += 256) {
    k6[u] = s64[(size_t)b*WND + u];
    k3[u] = s32[(size_t)b*WND + u];
    ix[u] = widx[(size_t)b*WND + u];
  }
  __syncthreads();
  if (threadIdx.x == 0 && b == 1) {
    for (int s = 0; s < WND-1; ++s) {
      const float ka = k3[s], kb = k3[s+1];
      const int ia = ix[s], ib = ix[s+1];
      const bool b_before_a = (kb > ka) || (kb == ka && ib < ia);
      if (b_before_a) {
        double t6 = k6[s]; k6[s] = k6[s+1]; k6[s+1] = t6;
        float  t3 = k3[s]; k3[s] = k3[s+1]; k3[s+1] = t3;
        int    ti = ix[s]; ix[s] = ix[s+1]; ix[s+1] = ti;
      }
    }
  }
  __syncthreads();
  for (int s = threadIdx.x; s < 512; s += 256) {
    ssc[(size_t)b*512 + s] = (float)k6[s];
    sidx[(size_t)b*512 + s] = ix[s];
  }
}

// ---------------- decode: 4 threads per slot (one exact chain each) ----------------
__global__ __launch_bounds__(256) void k_decode2(const double* __restrict__ h64,
                                                 const int* __restrict__ sidx,
                                                 const float* __restrict__ Wh,
                                                 const float* __restrict__ bh,
                                                 const float* __restrict__ anc,
                                                 float* __restrict__ sbx) {
  __shared__ double sm[64][4];
  const int b = blockIdx.y;
  const int ch = threadIdx.x & 3;
  const int sl = threadIdx.x >> 2;          // 0..63
  const int s  = blockIdx.x * 64 + sl;      // 8 blocks * 64 = 512 exact
  const int id = sidx[(size_t)b*512 + s];
  const int a = id / NPOS;
  const int p = id % NPOS;
  const double* hp = h64 + (size_t)b*HID*NPOS + p;
  const float*  wp = Wh + (size_t)(a*5+1+ch)*256;
  double acc = 0.0;
  for (int r = 0; r < 256; ++r)
    acc = fma(hp[(size_t)r*NPOS], (double)wp[r], acc);
  sm[sl][ch] = acc;
  __syncthreads();
  if (ch == 0) {
    const double t0 = sm[sl][0], t1 = sm[sl][1], t2 = sm[sl][2], t3 = sm[sl][3];
    const float tx = (float)(t0 + (double)bh[a*5+1]);
    const float ty = (float)(t1 + (double)bh[a*5+2]);
    const float tw = (float)(t2 + (double)bh[a*5+3]);
    const float th = (float)(t3 + (double)bh[a*5+4]);
    const int x = p % HW, y = p / HW;
    const float wa = anc[a*2+0], ha = anc[a*2+1];
    const float pxc = npadd((float)x + 0.5f, npmul(tx, wa));
    const float pyc = npadd((float)y + 0.5f, npmul(ty, ha));
    const float pw = npmul(wa, (float)exp((double)tw));
    const float ph = npmul(ha, (float)exp((double)th));
    const float hw_ = __fdiv_rn(pw, 2.0f);
    const float hh_ = __fdiv_rn(ph, 2.0f);
    float* bp = sbx + ((size_t)b*512 + s)*4;
    bp[0] = npsub(pxc, hw_);
    bp[1] = npsub(pyc, hh_);
    bp[2] = npadd(pxc, hw_);
    bp[3] = npadd(pyc, hh_);
  }
}

// ---------------- NMS: f32 IoU + serial scan + outputs ----------------
__global__ __launch_bounds__(512) void k_nms(const float* __restrict__ ssc,
                                             const float* __restrict__ sbx,
                                             float* __restrict__ out) {
  __shared__ float bxl[512][4];
  __shared__ float area[512];
  __shared__ float mscl[512];
  __shared__ unsigned long long rowb[512][8];
  __shared__ unsigned long long supw[8];
  __shared__ unsigned char keepf[512];
  const int b = blockIdx.x;
  const int tid = threadIdx.x;
  {
    const float* bp = sbx + ((size_t)b*512 + tid)*4;
    const float v0 = bp[0], v1 = bp[1], v2 = bp[2], v3 = bp[3];
    bxl[tid][0] = v0; bxl[tid][1] = v1; bxl[tid][2] = v2; bxl[tid][3] = v3;
    area[tid] = npmul(npsub(v2, v0), npsub(v3, v1));
    mscl[tid] = ssc[(size_t)b*512 + tid];
  }
  __syncthreads();
  {
    const float ax1 = bxl[tid][0], ay1 = bxl[tid][1];
    const float ax2 = bxl[tid][2], ay2 = bxl[tid][3];
    const float aa = area[tid];
    unsigned long long bits = 0;
    for (int j = 0; j < 512; ++j) {
      const float x1 = fmaxf(ax1, bxl[j][0]);
      const float y1 = fmaxf(ay1, bxl[j][1]);
      const float x2 = fminf(ax2, bxl[j][2]);
      const float y2 = fminf(ay2, bxl[j][3]);
      float iw = npsub(x2, x1); iw = (iw > 0.f) ? iw : 0.f;
      float ih = npsub(y2, y1); ih = (ih > 0.f) ? ih : 0.f;
      const float inter = npmul(iw, ih);
      const float un = npsub(npadd(aa, area[j]), inter);
      const float iou = __fdiv_rn(inter, fmaxf(un, 1e-8f));
      if (iou > 0.7f) bits |= (1ull << (j & 63));
      if ((j & 63) == 63) { rowb[tid][j >> 6] = bits; bits = 0; }
    }
  }
  __syncthreads();
  if (tid == 0) {
    for (int w = 0; w < 8; ++w) supw[w] = 0ull;
    for (int i = 0; i < 512; ++i) {
      const bool keep = (mscl[i] > 0.5f) &&
                        !((supw[i >> 6] >> (i & 63)) & 1ull);
      keepf[i] = keep ? 1 : 0;
      if (keep) {
        for (int w = 0; w < 8; ++w) supw[w] |= rowb[i][w];
      }
    }
  }
  __syncthreads();
  {
    const int row = b*512 + tid;
    const float kf = keepf[tid] ? 1.0f : 0.0f;
    #pragma unroll
    for (int c = 0; c < 4; ++c)
      out[(size_t)row*4 + c] = npmul(bxl[tid][c], kf);
    out[(size_t)2048*4 + row] = npmul(mscl[tid], kf);
    out[(size_t)2048*5 + row] = kf;
  }
}

extern "C" void kernel_launch(void* const* d_in, const int* in_sizes, int n_in,
                              void* d_out, int out_size, void* d_ws, size_t ws_size,
                              hipStream_t stream) {
  const float* feat = (const float*)d_in[0];
  const float* W1   = (const float*)d_in[1];
  const float* b1   = (const float*)d_in[2];
  const float* Wh   = (const float*)d_in[3];
  const float* bh   = (const float*)d_in[4];
  const float* anc  = (const float*)d_in[5];
  char* ws = (char*)d_ws;
  float*  W1t  = (float*)(ws + OFF_W1T);
  double* h64  = (double*)(ws + OFF_H64);
  float*  h32  = (float*)(ws + OFF_H32);
  double* k64  = (double*)(ws + OFF_K64);
  float*  k32  = (float*)(ws + OFF_K32);
  double* s64  = (double*)(ws + OFF_S64);
  float*  s32  = (float*)(ws + OFF_S32);
  int*    widx = (int*)(ws + OFF_WIDX);
  float*  ssc  = (float*)(ws + OFF_SSC);
  int*    sidx = (int*)(ws + OFF_SIDX);
  float*  sbx  = (float*)(ws + OFF_SBX);
  float* out = (float*)d_out;

  k_wt     <<<dim3(8,160),  256, 0, stream>>>(W1, W1t);
  k_conv   <<<dim3(4,36,5), 256, 0, stream>>>(W1t, feat, b1, h64, h32);
  k_head64 <<<dim3(81,4),   256, 0, stream>>>(h64, Wh, bh, k64);
  k_head32 <<<dim3(81),     256, 0, stream>>>(h32, Wh, bh, k32);
  k_rank   <<<dim3(81,4),   256, 0, stream>>>(k64, k32, s64, s32, widx);
  k_fix    <<<dim3(4),      256, 0, stream>>>(s64, s32, widx, ssc, sidx);
  k_decode2<<<dim3(8,4),    256, 0, stream>>>(h64, sidx, Wh, bh, anc, sbx);
  k_nms    <<<dim3(4),      512, 0, stream>>>(ssc, sbx, out);
}

// Round 17
// 4113.633 us; speedup vs baseline: 1.3418x; 1.3418x over previous
//
#include <hip/hip_runtime.h>
#include <stdint.h>
#include <math.h>

#define HW 48
#define CIN 1280
#define HID 256
#define NA 9
#define NPOS (HW*HW)       // 2304
#define NANCH (NA*NPOS)    // 20736
#define KTOT 11520
#define WND 640
#define NQ 720             // 9 taps * 80 chunks of 16

// ---------------- workspace layout (bytes) ----------------
#define OFF_W1T   ((size_t)0)                    // 11520*256*4 = 11796480
#define OFF_H64   (OFF_W1T + 11796480ull)        // 4*256*2304*8 = 18874368
#define OFF_H32   (OFF_H64 + 18874368ull)        // 256*2304*4 = 2359296 (batch1 only)
#define OFF_K64   (OFF_H32 + 2359296ull)         // 4*20736*8 = 663552
#define OFF_K32   (OFF_K64 + 663552ull)          // 20736*4 = 82944 (batch1 only)
#define OFF_S64   (OFF_K32 + 82944ull)           // 20480
#define OFF_S32   (OFF_S64 + 20480ull)           // 10240
#define OFF_WIDX  (OFF_S32 + 10240ull)           // 10240
#define OFF_SSC   (OFF_WIDX + 10240ull)          // 8192
#define OFF_SIDX  (OFF_SSC + 8192ull)            // 8192
#define OFF_SBX   (OFF_SIDX + 8192ull)           // 32768

__device__ __forceinline__ float npmul(float a, float b) { return __fmul_rn(a, b); }
__device__ __forceinline__ float npadd(float a, float b) { return __fadd_rn(a, b); }
__device__ __forceinline__ float npsub(float a, float b) { return __fsub_rn(a, b); }

// ---------------- W1 [256][11520] -> W1t [11520][256] (bit copy) ----------------
__global__ __launch_bounds__(256) void k_wt(const float* __restrict__ W1,
                                            float* __restrict__ W1t) {
  __shared__ float tile[32][73];
  const int co0 = blockIdx.x * 32;
  const int kt0 = blockIdx.y * 72;
  for (int u = threadIdx.x; u < 32*72; u += 256) {
    int co = u / 72, kt = u % 72;
    tile[co][kt] = W1[(size_t)(co0+co)*KTOT + kt0 + kt];
  }
  __syncthreads();
  for (int u = threadIdx.x; u < 32*72; u += 256) {
    int co = u % 32, kt = u / 32;
    W1t[(size_t)(kt0+kt)*256 + co0 + co] = tile[co][kt];
  }
}

// ---------------- unified conv, double-buffered f32 LDS staging ----------------
// z<4 = f64 path (batch z): per-tap c-chains (f64 fma), tap sums added in t order.
// z==4 = f32 path (batch 1): single fused f32 chain over k=(t,c).
// Chunk q = t*80 + c0/16, ascending — identical operand order to R15; only the
// staging (global->reg->LDS ping-pong, 1 barrier/chunk) changed.
__global__ __launch_bounds__(256) void k_conv(const float* __restrict__ W1t,
                                              const float* __restrict__ in,
                                              const float* __restrict__ b1,
                                              double* __restrict__ h64,
                                              float* __restrict__ h32) {
  __shared__ __align__(16) float As[2][16][68];
  __shared__ __align__(16) float Bs[2][16][68];
  const int z   = blockIdx.z;
  const int co0 = blockIdx.x * 64;
  const int p0  = blockIdx.y * 64;
  const int tid = threadIdx.x;
  const int col = (tid % 16) * 4;   // co in tile
  const int pl  = (tid / 16) * 4;   // p  in tile
  const int cA  = tid & 63;         // co for A-stage
  const int kA0 = tid >> 6;
  const int pp  = tid & 63;         // p for B-stage
  const int kB0 = tid >> 6;
  const int pB  = p0 + pp;
  const int yB  = pB / HW;
  const int xB  = pB - yB * HW;
  const int bsel = (z < 4) ? z : 1;
  const size_t bbase = (size_t)bsel * CIN * NPOS;

  float aR[4], bR[4];
  // ---- prefetch chunk 0 ----
  {
    const int t = 0, c0 = 0;
    const int yy = yB - 1, xx = xB - 1;
    const bool vB = ((unsigned)yy < (unsigned)HW) && ((unsigned)xx < (unsigned)HW);
    const size_t inoff = bbase + (size_t)(vB ? (yy*HW + xx) : 0);
    #pragma unroll
    for (int r = 0; r < 4; ++r)
      aR[r] = W1t[((size_t)(c0 + kA0 + 4*r)*9 + t)*256 + co0 + cA];
    #pragma unroll
    for (int r = 0; r < 4; ++r)
      bR[r] = vB ? in[inoff + (size_t)(c0 + kB0 + 4*r)*NPOS] : 0.f;
  }
  #pragma unroll
  for (int r = 0; r < 4; ++r) As[0][kA0 + 4*r][cA] = aR[r];
  #pragma unroll
  for (int r = 0; r < 4; ++r) Bs[0][kB0 + 4*r][pp] = bR[r];
  __syncthreads();

  if (z < 4) {
    // ================= f64 path =================
    double run[4][4], tap[4][4];
    #pragma unroll
    for (int i = 0; i < 4; ++i)
      #pragma unroll
      for (int j = 0; j < 4; ++j) tap[i][j] = 0.0;
    int cur = 0;
    for (int q = 0; q < NQ; ++q) {
      if (q < NQ-1) {
        const int qn = q + 1;
        const int t = qn / 80;
        const int c0 = (qn - t*80) * 16;
        const int yy = yB + t/3 - 1, xx = xB + t%3 - 1;
        const bool vB = ((unsigned)yy < (unsigned)HW) && ((unsigned)xx < (unsigned)HW);
        const size_t inoff = bbase + (size_t)(vB ? (yy*HW + xx) : 0);
        #pragma unroll
        for (int r = 0; r < 4; ++r)
          aR[r] = W1t[((size_t)(c0 + kA0 + 4*r)*9 + t)*256 + co0 + cA];
        #pragma unroll
        for (int r = 0; r < 4; ++r)
          bR[r] = vB ? in[inoff + (size_t)(c0 + kB0 + 4*r)*NPOS] : 0.f;
      }
      #pragma unroll
      for (int kc = 0; kc < 16; ++kc) {
        const float4 a4 = *(const float4*)&As[cur][kc][col];
        const float4 b4 = *(const float4*)&Bs[cur][kc][pl];
        const double av[4] = {(double)a4.x, (double)a4.y, (double)a4.z, (double)a4.w};
        const double bv[4] = {(double)b4.x, (double)b4.y, (double)b4.z, (double)b4.w};
        #pragma unroll
        for (int i = 0; i < 4; ++i)
          #pragma unroll
          for (int j = 0; j < 4; ++j)
            tap[i][j] = fma(av[i], bv[j], tap[i][j]);
      }
      if ((q % 80) == 79) {          // tap boundary: add in t order
        const int t = q / 80;
        if (t == 0) {
          #pragma unroll
          for (int i = 0; i < 4; ++i)
            #pragma unroll
            for (int j = 0; j < 4; ++j) { run[i][j] = tap[i][j]; tap[i][j] = 0.0; }
        } else {
          #pragma unroll
          for (int i = 0; i < 4; ++i)
            #pragma unroll
            for (int j = 0; j < 4; ++j) { run[i][j] = run[i][j] + tap[i][j]; tap[i][j] = 0.0; }
        }
      }
      if (q < NQ-1) {
        #pragma unroll
        for (int r = 0; r < 4; ++r) As[cur^1][kA0 + 4*r][cA] = aR[r];
        #pragma unroll
        for (int r = 0; r < 4; ++r) Bs[cur^1][kB0 + 4*r][pp] = bR[r];
        __syncthreads();
        cur ^= 1;
      }
    }
    #pragma unroll
    for (int i = 0; i < 4; ++i) {
      const int co = co0 + col + i;
      const double bias = (double)b1[co];
      #pragma unroll
      for (int j = 0; j < 4; ++j) {
        double v = run[i][j] + bias;
        v = (v >= 0.0) ? v : 0.01*v;
        h64[((size_t)bsel*HID + co)*NPOS + p0 + pl + j] = v;
      }
    }
  } else {
    // ================= f32 path, batch 1 =================
    float acc[4][4];
    #pragma unroll
    for (int i = 0; i < 4; ++i)
      #pragma unroll
      for (int j = 0; j < 4; ++j) acc[i][j] = 0.f;
    int cur = 0;
    for (int q = 0; q < NQ; ++q) {
      if (q < NQ-1) {
        const int qn = q + 1;
        const int t = qn / 80;
        const int c0 = (qn - t*80) * 16;
        const int yy = yB + t/3 - 1, xx = xB + t%3 - 1;
        const bool vB = ((unsigned)yy < (unsigned)HW) && ((unsigned)xx < (unsigned)HW);
        const size_t inoff = bbase + (size_t)(vB ? (yy*HW + xx) : 0);
        #pragma unroll
        for (int r = 0; r < 4; ++r)
          aR[r] = W1t[((size_t)(c0 + kA0 + 4*r)*9 + t)*256 + co0 + cA];
        #pragma unroll
        for (int r = 0; r < 4; ++r)
          bR[r] = vB ? in[inoff + (size_t)(c0 + kB0 + 4*r)*NPOS] : 0.f;
      }
      #pragma unroll
      for (int kc = 0; kc < 16; ++kc) {
        const float4 a4 = *(const float4*)&As[cur][kc][col];
        const float4 b4 = *(const float4*)&Bs[cur][kc][pl];
        const float av[4] = {a4.x, a4.y, a4.z, a4.w};
        const float bv[4] = {b4.x, b4.y, b4.z, b4.w};
        #pragma unroll
        for (int i = 0; i < 4; ++i)
          #pragma unroll
          for (int j = 0; j < 4; ++j)
            acc[i][j] = fmaf(av[i], bv[j], acc[i][j]);
      }
      if (q < NQ-1) {
        #pragma unroll
        for (int r = 0; r < 4; ++r) As[cur^1][kA0 + 4*r][cA] = aR[r];
        #pragma unroll
        for (int r = 0; r < 4; ++r) Bs[cur^1][kB0 + 4*r][pp] = bR[r];
        __syncthreads();
        cur ^= 1;
      }
    }
    #pragma unroll
    for (int i = 0; i < 4; ++i) {
      const int co = co0 + col + i;
      const float bias = b1[co];
      #pragma unroll
      for (int j = 0; j < 4; ++j) {
        float v = acc[i][j] + bias;
        v = (v >= 0.f) ? v : 0.01f*v;
        h32[(size_t)co*NPOS + p0 + pl + j] = v;
      }
    }
  }
}

// ---------------- head64: one thread per (p, a2) ----------------
__global__ __launch_bounds__(256) void k_head64(const double* __restrict__ h64,
                                                const float* __restrict__ Wh,
                                                const float* __restrict__ bh,
                                                double* __restrict__ key64) {
  const int b = blockIdx.y;
  const int gid = blockIdx.x * 256 + threadIdx.x;   // 20736 exact
  const int a2 = gid / NPOS;
  const int p  = gid - a2 * NPOS;
  const double* hp = h64 + (size_t)b*HID*NPOS + p;
  const float*  wp = Wh + (size_t)(a2*5)*256;
  double acc = 0.0;
  for (int k = 0; k < 256; ++k)
    acc = fma(hp[(size_t)k*NPOS], (double)wp[k], acc);
  const double c = acc + (double)bh[a2*5];
  const double s = 1.0 / (1.0 + exp(-c));
  key64[(size_t)b*NANCH + gid] = (s > 0.5) ? s : -1.0;
}

// ---------------- head32 (batch1): one thread per (p, a2) ----------------
__global__ __launch_bounds__(256) void k_head32(const float* __restrict__ h32,
                                                const float* __restrict__ Wh,
                                                const float* __restrict__ bh,
                                                float* __restrict__ key32) {
  const int gid = blockIdx.x * 256 + threadIdx.x;   // 20736 exact
  const int a2 = gid / NPOS;
  const int p  = gid - a2 * NPOS;
  const float* hp = h32 + p;
  const float* wp = Wh + (size_t)(a2*5)*256;
  float acc = 0.f;
  for (int k = 0; k < 256; ++k)
    acc = fmaf(hp[(size_t)k*NPOS], wp[k], acc);
  const float c = npadd(acc, bh[a2*5]);
  const float t = (float)exp(-(double)c);
  const float s = __fdiv_rn(1.0f, npadd(1.0f, t));
  key32[gid] = (s > 0.5f) ? s : -1.0f;
}

// ---------------- rank-select top-640 by f64 key (desc, index-asc ties) -----------
__global__ __launch_bounds__(256) void k_rank(const double* __restrict__ key64,
                                              const float* __restrict__ key32,
                                              double* __restrict__ s64,
                                              float* __restrict__ s32,
                                              int* __restrict__ widx) {
  __shared__ double tile[1024];
  const int b = blockIdx.y;
  const int i = blockIdx.x * 256 + threadIdx.x;
  const double ki = key64[(size_t)b*NANCH + i];
  int rank = 0;
  for (int j0 = 0; j0 < NANCH; j0 += 1024) {
    const int lim = (NANCH - j0 < 1024) ? (NANCH - j0) : 1024;
    for (int u = threadIdx.x; u < 1024; u += 256) {
      const int j = j0 + u;
      tile[u] = (j < NANCH) ? key64[(size_t)b*NANCH + j] : -1.0e300;
    }
    __syncthreads();
    for (int u = 0; u < lim; ++u) {
      const double kj = tile[u];
      const int j = j0 + u;
      if (kj > ki || (kj == ki && j < i)) ++rank;
    }
    __syncthreads();
  }
  if (rank < WND) {
    s64[(size_t)b*WND + rank] = ki;
    widx[(size_t)b*WND + rank] = i;
    if (b == 1) s32[(size_t)b*WND + rank] = key32[i];
  }
}

// ---------------- hybrid fix (LDS-staged): batch-1 discordances -> f32 order ------
__global__ __launch_bounds__(256) void k_fix(const double* __restrict__ s64,
                                             const float* __restrict__ s32,
                                             const int* __restrict__ widx,
                                             float* __restrict__ ssc,
                                             int* __restrict__ sidx) {
  __shared__ double k6[WND];
  __shared__ float  k3[WND];
  __shared__ int    ix[WND];
  const int b = blockIdx.x;
  for (int u = threadIdx.x; u < WND; u += 256) {
    k6[u] = s64[(size_t)b*WND + u];
    k3[u] = s32[(size_t)b*WND + u];
    ix[u] = widx[(size_t)b*WND + u];
  }
  __syncthreads();
  if (threadIdx.x == 0 && b == 1) {
    for (int s = 0; s < WND-1; ++s) {
      const float ka = k3[s], kb = k3[s+1];
      const int ia = ix[s], ib = ix[s+1];
      const bool b_before_a = (kb > ka) || (kb == ka && ib < ia);
      if (b_before_a) {
        double t6 = k6[s]; k6[s] = k6[s+1]; k6[s+1] = t6;
        float  t3 = k3[s]; k3[s] = k3[s+1]; k3[s+1] = t3;
        int    ti = ix[s]; ix[s] = ix[s+1]; ix[s+1] = ti;
      }
    }
  }
  __syncthreads();
  for (int s = threadIdx.x; s < 512; s += 256) {
    ssc[(size_t)b*512 + s] = (float)k6[s];
    sidx[(size_t)b*512 + s] = ix[s];
  }
}

// ---------------- decode: 4 threads per slot (one exact chain each) ----------------
__global__ __launch_bounds__(256) void k_decode2(const double* __restrict__ h64,
                                                 const int* __restrict__ sidx,
                                                 const float* __restrict__ Wh,
                                                 const float* __restrict__ bh,
                                                 const float* __restrict__ anc,
                                                 float* __restrict__ sbx) {
  __shared__ double sm[64][4];
  const int b = blockIdx.y;
  const int ch = threadIdx.x & 3;
  const int sl = threadIdx.x >> 2;
  const int s  = blockIdx.x * 64 + sl;
  const int id = sidx[(size_t)b*512 + s];
  const int a = id / NPOS;
  const int p = id % NPOS;
  const double* hp = h64 + (size_t)b*HID*NPOS + p;
  const float*  wp = Wh + (size_t)(a*5+1+ch)*256;
  double acc = 0.0;
  for (int r = 0; r < 256; ++r)
    acc = fma(hp[(size_t)r*NPOS], (double)wp[r], acc);
  sm[sl][ch] = acc;
  __syncthreads();
  if (ch == 0) {
    const double t0 = sm[sl][0], t1 = sm[sl][1], t2 = sm[sl][2], t3 = sm[sl][3];
    const float tx = (float)(t0 + (double)bh[a*5+1]);
    const float ty = (float)(t1 + (double)bh[a*5+2]);
    const float tw = (float)(t2 + (double)bh[a*5+3]);
    const float th = (float)(t3 + (double)bh[a*5+4]);
    const int x = p % HW, y = p / HW;
    const float wa = anc[a*2+0], ha = anc[a*2+1];
    const float pxc = npadd((float)x + 0.5f, npmul(tx, wa));
    const float pyc = npadd((float)y + 0.5f, npmul(ty, ha));
    const float pw = npmul(wa, (float)exp((double)tw));
    const float ph = npmul(ha, (float)exp((double)th));
    const float hw_ = __fdiv_rn(pw, 2.0f);
    const float hh_ = __fdiv_rn(ph, 2.0f);
    float* bp = sbx + ((size_t)b*512 + s)*4;
    bp[0] = npsub(pxc, hw_);
    bp[1] = npsub(pyc, hh_);
    bp[2] = npadd(pxc, hw_);
    bp[3] = npadd(pyc, hh_);
  }
}

// ---------------- NMS: f32 IoU + serial scan + outputs ----------------
__global__ __launch_bounds__(512) void k_nms(const float* __restrict__ ssc,
                                             const float* __restrict__ sbx,
                                             float* __restrict__ out) {
  __shared__ float bxl[512][4];
  __shared__ float area[512];
  __shared__ float mscl[512];
  __shared__ unsigned long long rowb[512][8];
  __shared__ unsigned long long supw[8];
  __shared__ unsigned char keepf[512];
  const int b = blockIdx.x;
  const int tid = threadIdx.x;
  {
    const float* bp = sbx + ((size_t)b*512 + tid)*4;
    const float v0 = bp[0], v1 = bp[1], v2 = bp[2], v3 = bp[3];
    bxl[tid][0] = v0; bxl[tid][1] = v1; bxl[tid][2] = v2; bxl[tid][3] = v3;
    area[tid] = npmul(npsub(v2, v0), npsub(v3, v1));
    mscl[tid] = ssc[(size_t)b*512 + tid];
  }
  __syncthreads();
  {
    const float ax1 = bxl[tid][0], ay1 = bxl[tid][1];
    const float ax2 = bxl[tid][2], ay2 = bxl[tid][3];
    const float aa = area[tid];
    unsigned long long bits = 0;
    for (int j = 0; j < 512; ++j) {
      const float x1 = fmaxf(ax1, bxl[j][0]);
      const float y1 = fmaxf(ay1, bxl[j][1]);
      const float x2 = fminf(ax2, bxl[j][2]);
      const float y2 = fminf(ay2, bxl[j][3]);
      float iw = npsub(x2, x1); iw = (iw > 0.f) ? iw : 0.f;
      float ih = npsub(y2, y1); ih = (ih > 0.f) ? ih : 0.f;
      const float inter = npmul(iw, ih);
      const float un = npsub(npadd(aa, area[j]), inter);
      const float iou = __fdiv_rn(inter, fmaxf(un, 1e-8f));
      if (iou > 0.7f) bits |= (1ull << (j & 63));
      if ((j & 63) == 63) { rowb[tid][j >> 6] = bits; bits = 0; }
    }
  }
  __syncthreads();
  if (tid == 0) {
    for (int w = 0; w < 8; ++w) supw[w] = 0ull;
    for (int i = 0; i < 512; ++i) {
      const bool keep = (mscl[i] > 0.5f) &&
                        !((supw[i >> 6] >> (i & 63)) & 1ull);
      keepf[i] = keep ? 1 : 0;
      if (keep) {
        for (int w = 0; w < 8; ++w) supw[w] |= rowb[i][w];
      }
    }
  }
  __syncthreads();
  {
    const int row = b*512 + tid;
    const float kf = keepf[tid] ? 1.0f : 0.0f;
    #pragma unroll
    for (int c = 0; c < 4; ++c)
      out[(size_t)row*4 + c] = npmul(bxl[tid][c], kf);
    out[(size_t)2048*4 + row] = npmul(mscl[tid], kf);
    out[(size_t)2048*5 + row] = kf;
  }
}

extern "C" void kernel_launch(void* const* d_in, const int* in_sizes, int n_in,
                              void* d_out, int out_size, void* d_ws, size_t ws_size,
                              hipStream_t stream) {
  const float* feat = (const float*)d_in[0];
  const float* W1   = (const float*)d_in[1];
  const float* b1   = (const float*)d_in[2];
  const float* Wh   = (const float*)d_in[3];
  const float* bh   = (const float*)d_in[4];
  const float* anc  = (const float*)d_in[5];
  char* ws = (char*)d_ws;
  float*  W1t  = (float*)(ws + OFF_W1T);
  double* h64  = (double*)(ws + OFF_H64);
  float*  h32  = (float*)(ws + OFF_H32);
  double* k64  = (double*)(ws + OFF_K64);
  float*  k32  = (float*)(ws + OFF_K32);
  double* s64  = (double*)(ws + OFF_S64);
  float*  s32  = (float*)(ws + OFF_S32);
  int*    widx = (int*)(ws + OFF_WIDX);
  float*  ssc  = (float*)(ws + OFF_SSC);
  int*    sidx = (int*)(ws + OFF_SIDX);
  float*  sbx  = (float*)(ws + OFF_SBX);
  float* out = (float*)d_out;

  k_wt     <<<dim3(8,160),  256, 0, stream>>>(W1, W1t);
  k_conv   <<<dim3(4,36,5), 256, 0, stream>>>(W1t, feat, b1, h64, h32);
  k_head64 <<<dim3(81,4),   256, 0, stream>>>(h64, Wh, bh, k64);
  k_head32 <<<dim3(81),     256, 0, stream>>>(h32, Wh, bh, k32);
  k_rank   <<<dim3(81,4),   256, 0, stream>>>(k64, k32, s64, s32, widx);
  k_fix    <<<dim3(4),      256, 0, stream>>>(s64, s32, widx, ssc, sidx);
  k_decode2<<<dim3(8,4),    256, 0, stream>>>(h64, sidx, Wh, bh, anc, sbx);
  k_nms    <<<dim3(4),      512, 0, stream>>>(ssc, sbx, out);
}